// Round 7
// baseline (214.089 us; speedup 1.0000x reference)
//
#include <hip/hip_runtime.h>
#include <cmath>

#define B_   128
#define H_   256
#define W_   256
#define WC_  129
#define L_   182
#define NS0  65        // block c=0 owns spectrum slots s in [0,65); c=1 owns [65,129)
#define SPEC_PAD 257   // y-dim pad (odd) -> conflict-free writes and reads
#define PI_F 3.14159265358979f

// ---------------------------------------------------------------------------
// Two interleaved wave-synchronous 256-point DIF FFTs across one 64-lane wave.
// FFT A in slots 0..3, FFT B in slots 4..7; slot j holds x[l + 64*(j&3)].
// Twiddles shared (half the sincos); two independent shfl chains for ILP.
// Output: storage q = l + 64*(j&3) holds X[bitrev8(q)] of the respective FFT.
// ---------------------------------------------------------------------------
__device__ __forceinline__ void fft256x2_wave(float vr[8], float vi[8], int l) {
  float c0, s0;
  __sincosf(-2.f * PI_F * (float)l / 256.f, &s0, &c0);  // W256^l
  float c1 = s0, s1 = -c0;                              // W256^(l+64)
  float c2 = c0 * c0 - s0 * s0, s2 = 2.f * c0 * s0;     // W128^l
  #pragma unroll
  for (int f = 0; f < 8; f += 4) {
    float ur = vr[f+0] + vr[f+2], ui = vi[f+0] + vi[f+2];
    float dr = vr[f+0] - vr[f+2], di = vi[f+0] - vi[f+2];
    vr[f+0] = ur; vi[f+0] = ui;
    vr[f+2] = dr * c0 - di * s0; vi[f+2] = dr * s0 + di * c0;
    ur = vr[f+1] + vr[f+3]; ui = vi[f+1] + vi[f+3];
    dr = vr[f+1] - vr[f+3]; di = vi[f+1] - vi[f+3];
    vr[f+1] = ur; vi[f+1] = ui;
    vr[f+3] = dr * c1 - di * s1; vi[f+3] = dr * s1 + di * c1;
    ur = vr[f+0] + vr[f+1]; ui = vi[f+0] + vi[f+1];
    dr = vr[f+0] - vr[f+1]; di = vi[f+0] - vi[f+1];
    vr[f+0] = ur; vi[f+0] = ui;
    vr[f+1] = dr * c2 - di * s2; vi[f+1] = dr * s2 + di * c2;
    ur = vr[f+2] + vr[f+3]; ui = vi[f+2] + vi[f+3];
    dr = vr[f+2] - vr[f+3]; di = vi[f+2] - vi[f+3];
    vr[f+2] = ur; vi[f+2] = ui;
    vr[f+3] = dr * c2 - di * s2; vi[f+3] = dr * s2 + di * c2;
  }
  #pragma unroll
  for (int h = 32; h >= 1; h >>= 1) {
    int i = l & (h - 1);
    float c, s;
    __sincosf(-PI_F * (float)i / (float)h, &s, &c);
    bool up = (l & h) != 0;
    float cc = up ? c : 1.f;
    float ss = up ? s : 0.f;
    float sgn = up ? -1.f : 1.f;
    #pragma unroll
    for (int j = 0; j < 8; ++j) {
      float br = __shfl_xor(vr[j], h, 64);
      float bi = __shfl_xor(vi[j], h, 64);
      float tr = fmaf(sgn, vr[j], br);
      float ti = fmaf(sgn, vi[j], bi);
      vr[j] = tr * cc - ti * ss;
      vi[j] = tr * ss + ti * cc;
    }
  }
}

// ---------------------------------------------------------------------------
// Fused rows+cols kernel. 2 blocks per image (256 blocks = 1 per CU).
// Each block row-FFTs ALL 256 rows of its image (sibling's duplicate image
// read hits L2/L3: the 787 KB image trivially caches) but keeps only its 65
// (or 64) spectrum columns in LDS, then col-FFTs them, log-power-bins into
// LDS, and plain-stores partial[b][c][L]. No inter buffer, no grid sync.
// Spectrum compaction: rfft keeps kx = bitrev8(q) <= 128 <=> q even (s=q/2,
// kx = bitrev7(s)) or q==1 (s=128, kx=128). spec[s][y] y-padded to 257:
// row-phase writes (lanes vary s, consecutive) and col-phase reads (lanes
// vary y, consecutive) are both bank-conflict-free.
// ---------------------------------------------------------------------------
__global__ __launch_bounds__(1024) void mega_kernel(
    const float* __restrict__ data, const int* __restrict__ radius,
    float* __restrict__ partial, float* __restrict__ cntpart) {
  __shared__ float specR[NS0 * SPEC_PAD];   // 66,820 B
  __shared__ float specI[NS0 * SPEC_PAD];   // 66,820 B
  __shared__ float lbins[L_];
  __shared__ float lcnt[L_];
  int tid = threadIdx.x;
  int w = tid >> 6, l = tid & 63;
  int b = blockIdx.x >> 1;
  int c = blockIdx.x & 1;
  int s_base = c ? NS0 : 0;
  int ns = c ? (WC_ - NS0) : NS0;           // 64 : 65
  bool do_cnt = (b == 0);
  for (int i = tid; i < L_; i += 1024) { lbins[i] = 0.f; lcnt[i] = 0.f; }
  const float* base = data + (size_t)b * 3 * (H_ * W_);

  // ---- Row phase: 8 rounds x 16 waves x 2 rows = 256 row FFTs -------------
  // Waves write disjoint (s,y) cells (y unique per wave+round): no barrier
  // inside the phase.
  for (int t = 0; t < 8; ++t) {
    int yA = t * 32 + w;
    int yB = yA + 16;
    const float* pA = base + (size_t)yA * W_;
    const float* pB = base + (size_t)yB * W_;
    float vr[8], vi[8];
    #pragma unroll
    for (int j = 0; j < 4; ++j) {
      int x = l + 64 * j;
      float r = pA[x], g = pA[H_ * W_ + x], bl = pA[2 * H_ * W_ + x];
      vr[j] = fmaf(0.299f, r, fmaf(0.587f, g, 0.114f * bl));
      vi[j] = 0.f;
      r = pB[x]; g = pB[H_ * W_ + x]; bl = pB[2 * H_ * W_ + x];
      vr[4 + j] = fmaf(0.299f, r, fmaf(0.587f, g, 0.114f * bl));
      vi[4 + j] = 0.f;
    }
    fft256x2_wave(vr, vi, l);
    #pragma unroll
    for (int j = 0; j < 4; ++j) {
      int q = l + 64 * j;
      int s = (q & 1) ? ((q == 1) ? 128 : -1) : (q >> 1);
      if (s >= s_base && s < s_base + ns) {
        int sl = s - s_base;
        specR[sl * SPEC_PAD + yA] = vr[j];
        specI[sl * SPEC_PAD + yA] = vi[j];
        specR[sl * SPEC_PAD + yB] = vr[4 + j];
        specI[sl * SPEC_PAD + yB] = vi[4 + j];
      }
    }
  }
  __syncthreads();

  // ---- Col phase: 3 rounds x 16 waves x 2 cols covers ns<=65 columns ------
  for (int t = 0; t < 3; ++t) {
    int sA = t * 32 + w;
    int sB = sA + 16;
    bool vA = sA < ns, vB = sB < ns;
    int eA = vA ? sA : 0, eB = vB ? sB : 0;
    float vr[8], vi[8];
    #pragma unroll
    for (int j = 0; j < 4; ++j) {
      int y = l + 64 * j;
      vr[j]     = specR[eA * SPEC_PAD + y];
      vi[j]     = specI[eA * SPEC_PAD + y];
      vr[4 + j] = specR[eB * SPEC_PAD + y];
      vi[4 + j] = specI[eB * SPEC_PAD + y];
    }
    fft256x2_wave(vr, vi, l);
    int sgA = s_base + eA, sgB = s_base + eB;
    int kxA = (sgA == 128) ? 128 : (int)(__brev((unsigned)(2 * sgA)) >> 24);
    int kxB = (sgB == 128) ? 128 : (int)(__brev((unsigned)(2 * sgB)) >> 24);
    int rb = 4 * (int)(__brev((unsigned)l) >> 26);
    #pragma unroll
    for (int j = 0; j < 4; ++j) {
      int ky = rb + ((j == 1) ? 2 : (j == 2) ? 1 : j);  // bitrev8(l+64j)
      if (vA) {
        int bin = radius[ky * WC_ + kxA];
        float pw = vr[j] * vr[j] + vi[j] * vi[j];
        atomicAdd(&lbins[bin], 20.f * __logf(pw + 1e-8f));
        if (do_cnt) atomicAdd(&lcnt[bin], 1.f);
      }
      if (vB) {
        int bin = radius[ky * WC_ + kxB];
        float pw = vr[4 + j] * vr[4 + j] + vi[4 + j] * vi[4 + j];
        atomicAdd(&lbins[bin], 20.f * __logf(pw + 1e-8f));
        if (do_cnt) atomicAdd(&lcnt[bin], 1.f);
      }
    }
  }
  __syncthreads();
  float* pp = partial + ((size_t)b * 2 + c) * L_;
  for (int i = tid; i < L_; i += 1024) pp[i] = lbins[i];
  if (do_cnt) {
    float* cp = cntpart + (size_t)c * L_;
    for (int i = tid; i < L_; i += 1024) cp[i] = lcnt[i];
  }
}

// One block per batch sample (r0-verbatim, NG=2): reduce 2 value+count
// partials, segment mean, min-max normalize, L1 vs mean. Plain stores.
__global__ __launch_bounds__(256) void loss_kernel(
    const float* __restrict__ partial, const float* __restrict__ cntpart,
    const float* __restrict__ mean, float* __restrict__ lpart) {
  int b = blockIdx.x;
  int t = threadIdx.x;
  __shared__ float prof[L_];
  __shared__ float red[256];
  if (t < L_) {
    const float* pb = partial + (size_t)b * 2 * L_;
    float acc  = pb[t] + pb[L_ + t];
    float csum = cntpart[t] + cntpart[L_ + t];
    prof[t] = acc / csum;
  }
  __syncthreads();
  red[t] = (t < L_) ? prof[t] : INFINITY;
  __syncthreads();
  for (int s = 128; s > 0; s >>= 1) {
    if (t < s) red[t] = fminf(red[t], red[t + s]);
    __syncthreads();
  }
  float mn = red[0];
  __syncthreads();
  red[t] = (t < L_) ? (prof[t] - mn) : -INFINITY;
  __syncthreads();
  for (int s = 128; s > 0; s >>= 1) {
    if (t < s) red[t] = fmaxf(red[t], red[t + s]);
    __syncthreads();
  }
  float mx = red[0];
  __syncthreads();
  red[t] = (t < L_) ? fabsf((prof[t] - mn) / mx - mean[t]) : 0.f;
  __syncthreads();
  for (int s = 128; s > 0; s >>= 1) {
    if (t < s) red[t] += red[t + s];
    __syncthreads();
  }
  if (t == 0) lpart[b] = red[0];
}

// Final: one wave sums the 128 per-sample losses, plain store to out.
__global__ __launch_bounds__(64) void final_kernel(
    const float* __restrict__ lpart, float* __restrict__ out) {
  int l = threadIdx.x;
  float v = lpart[l] + lpart[l + 64];
  #pragma unroll
  for (int h = 32; h >= 1; h >>= 1) v += __shfl_xor(v, h, 64);
  if (l == 0) out[0] = v;
}

extern "C" void kernel_launch(void* const* d_in, const int* in_sizes, int n_in,
                              void* d_out, int out_size, void* d_ws, size_t ws_size,
                              hipStream_t stream) {
  const float* data   = (const float*)d_in[0];  // [128,3,256,256] f32
  const float* mean   = (const float*)d_in[1];  // [182] f32
  const int*   radius = (const int*)d_in[2];    // [256,129] i32
  float* out = (float*)d_out;                   // scalar f32

  float* partial = (float*)d_ws;                // [B][2][L]
  float* cntpart = partial + (size_t)B_ * 2 * L_;  // [2][L]
  float* lpart   = cntpart + (size_t)2 * L_;    // [B]

  mega_kernel<<<B_ * 2, 1024, 0, stream>>>(data, radius, partial, cntpart);
  loss_kernel<<<B_, 256, 0, stream>>>(partial, cntpart, mean, lpart);
  final_kernel<<<1, 64, 0, stream>>>(lpart, out);
}